// Round 1
// baseline (325.962 us; speedup 1.0000x reference)
//
#include <hip/hip_runtime.h>
#include <math.h>

#define N 4096
#define THREADS 256
#define BATCH 8192

// Base-16 digit swizzle: d0 ^= d1 ^ d2. Involution on [0,4096).
// Every LDS access family in this kernel (lane-contiguous {t+256p},
// stride-16 {i1+16k+256c}, per-thread-contiguous {j+16b+256a}) lands at
// <=4 lanes per bank-pair for b64 accesses -- measured-free on CDNA4
// (current kernel: SQ_LDS_BANK_CONFLICT == 0 with the same 4-way pattern).
#define SWZ(i) ((i) ^ (((i) >> 4) & 15) ^ (((i) >> 8) & 15))
// dft16 stores X_p at slot IDX16(p) (base-4 digit swap; involution)
#define IDX16(p) ((((p) & 3) << 2) | ((p) >> 2))

__device__ __forceinline__ float2 cmul(float2 a, float2 b) {
    return make_float2(fmaf(a.x, b.x, -(a.y * b.y)), fmaf(a.x, b.y, a.y * b.x));
}
// a * conj(b)
__device__ __forceinline__ float2 cmulc(float2 a, float2 b) {
    return make_float2(fmaf(a.x, b.x, a.y * b.y), fmaf(a.y, b.x, -(a.x * b.y)));
}

// radix-4 butterfly at v[base + r*stride]; forward uses w4 = -i, inverse +i
template<bool INV>
__device__ __forceinline__ void dft4(float2* v, int base, int stride) {
    float2 a = v[base], b = v[base + stride], c = v[base + 2 * stride], d = v[base + 3 * stride];
    float2 t0 = make_float2(a.x + c.x, a.y + c.y);
    float2 t1 = make_float2(a.x - c.x, a.y - c.y);
    float2 t2 = make_float2(b.x + d.x, b.y + d.y);
    float2 t3 = make_float2(b.x - d.x, b.y - d.y);
    float2 j3 = INV ? make_float2(-t3.y, t3.x) : make_float2(t3.y, -t3.x);
    v[base]              = make_float2(t0.x + t2.x, t0.y + t2.y);
    v[base + stride]     = make_float2(t1.x + j3.x, t1.y + j3.y);
    v[base + 2 * stride] = make_float2(t0.x - t2.x, t0.y - t2.y);
    v[base + 3 * stride] = make_float2(t1.x - j3.x, t1.y - j3.y);
}

// internal W16^{n1*k2} twiddles; slot set symmetric under n1<->k2.
template<bool INV>
__device__ __forceinline__ void tw16(float2* v) {
    const float C1 = 0.9238795325112867f;
    const float S1 = 0.3826834323650898f;
    const float R2 = 0.7071067811865476f;
    const float s = INV ? 1.0f : -1.0f;
    const float2 W1 = make_float2(C1, s * S1);
    const float2 W2 = make_float2(R2, s * R2);
    const float2 W3 = make_float2(S1, s * C1);
    const float2 W6 = make_float2(-R2, s * R2);
    const float2 W9 = make_float2(-C1, -s * S1);
    v[5]  = cmul(v[5],  W1);
    v[9]  = cmul(v[9],  W2);
    v[13] = cmul(v[13], W3);
    v[6]  = cmul(v[6],  W2);
    { float2 z = v[10]; v[10] = INV ? make_float2(-z.y, z.x) : make_float2(z.y, -z.x); }
    v[14] = cmul(v[14], W6);
    v[7]  = cmul(v[7],  W3);
    v[11] = cmul(v[11], W6);
    v[15] = cmul(v[15], W9);
}

// input sample n at v[n]; output X_p at v[IDX16(p)]
template<bool INV>
__device__ __forceinline__ void dft16(float2* v) {
    #pragma unroll
    for (int n1 = 0; n1 < 4; ++n1) dft4<INV>(v, n1, 4);
    tw16<INV>(v);
    #pragma unroll
    for (int k2 = 0; k2 < 4; ++k2) dft4<INV>(v, 4 * k2, 1);
}

// input sample n at v[IDX16(n)]; output X_p at v[p]
template<bool INV>
__device__ __forceinline__ void dft16_perm(float2* v) {
    #pragma unroll
    for (int n1 = 0; n1 < 4; ++n1) dft4<INV>(v, 4 * n1, 1);
    tw16<INV>(v);
    #pragma unroll
    for (int k2 = 0; k2 < 4; ++k2) dft4<INV>(v, k2, 4);
}

// v[IDX16(p)] *= w1^p, p=1..15. Powers generated in registers from the
// exact (double-precision-tabulated) base: two independent 7-deep chains.
// Replaces 15 multi-line tw[] gathers per call.
__device__ __forceinline__ void twiddle_fwd(float2* v, float2 w1) {
    float2 w2 = cmul(w1, w1);
    float2 wo = w1, we = w2;
    v[IDX16(1)] = cmul(v[IDX16(1)], wo);
    v[IDX16(2)] = cmul(v[IDX16(2)], we);
    #pragma unroll
    for (int p = 3; p < 16; p += 2) { wo = cmul(wo, w2); v[IDX16(p)] = cmul(v[IDX16(p)], wo); }
    #pragma unroll
    for (int p = 4; p < 16; p += 2) { we = cmul(we, w2); v[IDX16(p)] = cmul(v[IDX16(p)], we); }
}

// v[p] *= conj(w1^p), p=1..15 (natural slots; applied BEFORE the conj dft)
__device__ __forceinline__ void twiddle_inv(float2* v, float2 w1) {
    float2 w2 = cmul(w1, w1);
    float2 wo = w1, we = w2;
    v[1] = cmulc(v[1], wo);
    v[2] = cmulc(v[2], we);
    #pragma unroll
    for (int p = 3; p < 16; p += 2) { wo = cmul(wo, w2); v[p] = cmulc(v[p], wo); }
    #pragma unroll
    for (int p = 4; p < 16; p += 2) { we = cmul(we, w2); v[p] = cmulc(v[p], we); }
}

// ---------------------------------------------------------------------------
// prep: full Hermitian spectrum H[0..N) and twiddle table tw[0..N)
// (hot kernel now reads only tw[t] and tw[16*(t&15)] -- bases for the
//  register-generated powers)
// ---------------------------------------------------------------------------
__global__ void prep_kernel(const float* __restrict__ wr, const float* __restrict__ wi,
                            float2* __restrict__ H, float2* __restrict__ tw) {
    int i = blockIdx.x * blockDim.x + threadIdx.x;
    if (i < N) {
        double ang = -2.0 * M_PI * (double)i / (double)N;
        tw[i] = make_float2((float)cos(ang), (float)sin(ang));
        float re, im;
        if (i <= N / 2) {
            re = wr[i];
            im = (i == N / 2) ? 0.0f : wi[i];
        } else {
            re = wr[N - i];
            im = -wi[N - i];
        }
        H[i] = make_float2(re, im);
    }
}

// ---------------------------------------------------------------------------
// One block = 2 rows packed as one complex sequence (z = x1 + i*x2).
// In-place DIF (fwd) -> DIT (inv) radix-16, owner-computes groups: every
// stage's per-thread read set == write set, so each stage boundary needs
// exactly ONE barrier (4 total vs 7 for the Stockham form). The forward
// last stage + H-multiply + inverse first stage are fused in registers;
// the digit-reversed middle ordering is absorbed into the H index, which
// stays perfectly coalesced (H[t + 256*khat]).
//   fwd S1: groups {t+256r},       twiddle W_N^{t p}
//   fwd S2: groups {i1+16r+256hi}, twiddle W_256^{i1 p}
//   middle: groups {j+16hi+256i1}: dft16, *H, conj dft16  (all in regs)
//   inv S2: conj-twiddle then conj dft16, same groups as fwd S2
//   inv S1: conj-twiddle then conj dft16, 1/N + bias epilogue to global
// ---------------------------------------------------------------------------
__global__ __launch_bounds__(THREADS, 4) void fft_conv_kernel(
        const float* __restrict__ x, const float2* __restrict__ H,
        const float2* __restrict__ tw, const float* __restrict__ bias,
        float* __restrict__ out) {
    __shared__ float2 lds[N];   // 32 KB -> up to 5 blocks/CU
    const int t  = threadIdx.x;
    const int i1 = t & 15;
    const int hi = t >> 4;
    const long base1 = (long)(2 * blockIdx.x) * N;
    const long base2 = base1 + N;

    // base twiddles: coalesced (tw[t]) / 16-line broadcast (tw[16*i1]);
    // issued early so they fly with the x loads.
    const float2 w1 = tw[t];        // W_N^t
    const float2 wb = tw[16 * i1];  // W_256^{i1}

    float2 v[16];

    // ---- load: pattern {t + 256 r} straight from global (coalesced) ----
    #pragma unroll
    for (int r = 0; r < 16; ++r) {
        v[r].x = x[base1 + t + 256 * r];
        v[r].y = x[base2 + t + 256 * r];
    }

    // ---- fwd S1: dft16 over r, W_N^{t p}, write back to own slot set ----
    dft16<false>(v);
    twiddle_fwd(v, w1);
    #pragma unroll
    for (int p = 0; p < 16; ++p)
        lds[SWZ(t + 256 * p)] = v[IDX16(p)];
    __syncthreads();                                        // (1)

    // ---- fwd S2: groups {i1 + 16r + 256 hi} ----
    #pragma unroll
    for (int r = 0; r < 16; ++r) v[r] = lds[SWZ(i1 + 16 * r + 256 * hi)];
    dft16<false>(v);
    twiddle_fwd(v, wb);
    #pragma unroll
    for (int p = 0; p < 16; ++p)
        lds[SWZ(i1 + 16 * p + 256 * hi)] = v[IDX16(p)];
    __syncthreads();                                        // (2)

    // ---- middle: groups {j + 16 hi + 256 i1}; spectral index of the
    //      dft16 output at slot IDX16(khat) is (t + 256 khat) -> H coalesced.
    #pragma unroll
    for (int j = 0; j < 16; ++j) v[j] = lds[SWZ(j + 16 * hi + 256 * i1)];
    dft16<false>(v);
    #pragma unroll
    for (int q = 0; q < 16; ++q)
        v[q] = cmul(v[q], H[t + 256 * IDX16(q)]);
    dft16_perm<true>(v);                                    // conj dft over khat
    #pragma unroll
    for (int j = 0; j < 16; ++j)
        lds[SWZ(j + 16 * hi + 256 * i1)] = v[j];
    __syncthreads();                                        // (3)

    // ---- inv S2: conj twiddle FIRST, then conj dft16; same slot set ----
    #pragma unroll
    for (int p = 0; p < 16; ++p) v[p] = lds[SWZ(i1 + 16 * p + 256 * hi)];
    twiddle_inv(v, wb);
    dft16<true>(v);
    #pragma unroll
    for (int r = 0; r < 16; ++r)
        lds[SWZ(i1 + 16 * r + 256 * hi)] = v[IDX16(r)];
    __syncthreads();                                        // (4)

    // ---- inv S1 + scale/bias epilogue straight to global ----
    #pragma unroll
    for (int p = 0; p < 16; ++p) v[p] = lds[SWZ(t + 256 * p)];
    twiddle_inv(v, w1);
    dft16<true>(v);
    const float inv = 1.0f / (float)N;
    #pragma unroll
    for (int r = 0; r < 16; ++r) {
        float2 val = v[IDX16(r)];
        float bb = bias[t + 256 * r];
        out[base1 + t + 256 * r] = fmaf(val.x, inv, bb);
        out[base2 + t + 256 * r] = fmaf(val.y, inv, bb);
    }
}

// ---------------------------------------------------------------------------
extern "C" void kernel_launch(void* const* d_in, const int* in_sizes, int n_in,
                              void* d_out, int out_size, void* d_ws, size_t ws_size,
                              hipStream_t stream) {
    const float* x  = (const float*)d_in[0];   // (8192, 4096)
    const float* wr = (const float*)d_in[1];   // (2049,)
    const float* wi = (const float*)d_in[2];   // (2049,)
    const float* bs = (const float*)d_in[3];   // (4096,)
    float* out = (float*)d_out;                // (8192, 4096)

    float2* H  = (float2*)d_ws;                                       // 32 KB
    float2* tw = (float2*)((char*)d_ws + (size_t)N * sizeof(float2)); // 32 KB

    prep_kernel<<<dim3(N / THREADS), dim3(THREADS), 0, stream>>>(wr, wi, H, tw);
    fft_conv_kernel<<<dim3(BATCH / 2), dim3(THREADS), 0, stream>>>(x, H, tw, bs, out);
}